// Round 2
// baseline (1239.184 us; speedup 1.0000x reference)
//
#include <hip/hip_runtime.h>

// RNN: h_{t+1} = tanh(W h_t + w_bias + V x_t + v_bias)
// x: [S,B,I] f32; W: [H,H]; V: [H,I]; out = h_seq [S,B,H] ++ h_final [B,H]
// S=2048 B=2048 I=16 H=64.
//
// Mapping: 1 wave per batch row; lane j owns hidden unit j.
// R2 change: W row (64 f32) and V row (16 f32) held as NAMED float4 registers
// (R1 used C arrays -> compiler demoted them out of VGPRs; VGPR_Count was 64,
// per-step reloads dominated). No other structural change.

constexpr int S = 2048, B = 2048, I = 16, H = 64;
constexpr int CH = 64;  // timesteps of x staged per chunk

__global__ void rnn_fused(const float* __restrict__ x,
                          const float* __restrict__ Wm,
                          const float* __restrict__ wb,
                          const float* __restrict__ Vm,
                          const float* __restrict__ vb,
                          float* __restrict__ out)
{
    const int j = threadIdx.x;   // 0..63 = hidden unit
    const int b = blockIdx.x;    // batch row

    __shared__ __align__(16) float xs[CH][I];  // 4 KB, wave-private
    __shared__ __align__(16) float hs[H];      // 256 B, wave-private

    // ---- W row j: 16 named float4 (64 VGPRs), V row j: 4 named float4 ----
    const float4* wrow = (const float4*)(Wm + j * H);
    const float4 w0 = wrow[0],  w1 = wrow[1],  w2 = wrow[2],  w3 = wrow[3];
    const float4 w4 = wrow[4],  w5 = wrow[5],  w6 = wrow[6],  w7 = wrow[7];
    const float4 w8 = wrow[8],  w9 = wrow[9],  w10 = wrow[10], w11 = wrow[11];
    const float4 w12 = wrow[12], w13 = wrow[13], w14 = wrow[14], w15 = wrow[15];
    const float4* vrow = (const float4*)(Vm + j * I);
    const float4 v0 = vrow[0], v1 = vrow[1], v2 = vrow[2], v3 = vrow[3];
    const float bias = wb[j] + vb[j];

    hs[j] = 0.0f;        // h0 = 0
    float h = 0.0f;

    float* op = out + (size_t)b * H + j;   // h_seq[t][b][j], stride B*H per t
    const float* xb = x + (size_t)b * I;   // x[t][b][i], stride B*I per t

    for (int t0 = 0; t0 < S; t0 += CH) {
        // ---- stage x[t0 .. t0+CH) for this batch row (wave-private LDS) ----
#pragma unroll
        for (int m = 0; m < (CH * I) / (4 * 64); ++m) {  // 4 float4 per lane
            int q = j + 64 * m;          // float4 index in [0, 256)
            int tl = q >> 2, i4 = q & 3;
            float4 t4 = *(const float4*)(xb + (size_t)(t0 + tl) * (B * I) + i4 * 4);
            *(float4*)(&xs[tl][i4 * 4]) = t4;
        }
        // (no barrier: LDS tile is private to this wave)

        for (int tt = 0; tt < CH; ++tt) {
            const float4* h4 = (const float4*)hs;
            float a0 = bias, a1 = 0.f, a2 = 0.f, a3 = 0.f;
            float a4 = 0.f, a5 = 0.f, a6 = 0.f, a7 = 0.f;

            // W h: 16 broadcast ds_read_b128 + 64 FMAs, 8 independent chains
#define ACC_Q(q, A0, A1, A2, A3)                         \
            { float4 hq = h4[q];                         \
              A0 = fmaf(hq.x, w##q.x, A0);               \
              A1 = fmaf(hq.y, w##q.y, A1);               \
              A2 = fmaf(hq.z, w##q.z, A2);               \
              A3 = fmaf(hq.w, w##q.w, A3); }
            ACC_Q(0,  a0, a1, a2, a3)
            ACC_Q(1,  a4, a5, a6, a7)
            ACC_Q(2,  a0, a1, a2, a3)
            ACC_Q(3,  a4, a5, a6, a7)
            ACC_Q(4,  a0, a1, a2, a3)
            ACC_Q(5,  a4, a5, a6, a7)
            ACC_Q(6,  a0, a1, a2, a3)
            ACC_Q(7,  a4, a5, a6, a7)
            ACC_Q(8,  a0, a1, a2, a3)
            ACC_Q(9,  a4, a5, a6, a7)
            ACC_Q(10, a0, a1, a2, a3)
            ACC_Q(11, a4, a5, a6, a7)
            ACC_Q(12, a0, a1, a2, a3)
            ACC_Q(13, a4, a5, a6, a7)
            ACC_Q(14, a0, a1, a2, a3)
            ACC_Q(15, a4, a5, a6, a7)
#undef ACC_Q

            // V x_t: 4 broadcast ds_read_b128 + 16 FMAs
            const float4* x4 = (const float4*)xs[tt];
            {
                float4 xa = x4[0];
                a0 = fmaf(xa.x, v0.x, a0);  a1 = fmaf(xa.y, v0.y, a1);
                a2 = fmaf(xa.z, v0.z, a2);  a3 = fmaf(xa.w, v0.w, a3);
                float4 xbv = x4[1];
                a4 = fmaf(xbv.x, v1.x, a4); a5 = fmaf(xbv.y, v1.y, a5);
                a6 = fmaf(xbv.z, v1.z, a6); a7 = fmaf(xbv.w, v1.w, a7);
                float4 xc = x4[2];
                a0 = fmaf(xc.x, v2.x, a0);  a1 = fmaf(xc.y, v2.y, a1);
                a2 = fmaf(xc.z, v2.z, a2);  a3 = fmaf(xc.w, v2.w, a3);
                float4 xd = x4[3];
                a4 = fmaf(xd.x, v3.x, a4);  a5 = fmaf(xd.y, v3.y, a5);
                a6 = fmaf(xd.z, v3.z, a6);  a7 = fmaf(xd.w, v3.w, a7);
            }

            float pre = ((a0 + a1) + (a2 + a3)) + ((a4 + a5) + (a6 + a7));

            // tanh(pre) = 1 - 2/(exp(2*pre)+1); exp via v_exp_f32 (exp2)
            float e = __builtin_amdgcn_exp2f(pre * 2.8853900817779268f);
            float r = __builtin_amdgcn_rcpf(e + 1.0f);
            h = fmaf(-2.0f, r, 1.0f);

            hs[j] = h;                               // feed next step
            *op = h;                                 // h_seq store, coalesced
            op += B * H;
        }
    }
    // final h (second tuple element), after h_seq
    out[(size_t)S * B * H + (size_t)b * H + j] = h;
}

extern "C" void kernel_launch(void* const* d_in, const int* in_sizes, int n_in,
                              void* d_out, int out_size, void* d_ws, size_t ws_size,
                              hipStream_t stream) {
    const float* x  = (const float*)d_in[0];
    const float* Wm = (const float*)d_in[1];
    const float* wb = (const float*)d_in[2];
    const float* Vm = (const float*)d_in[3];
    const float* vb = (const float*)d_in[4];
    float* out = (float*)d_out;

    rnn_fused<<<B, 64, 0, stream>>>(x, Wm, wb, Vm, vb, out);
}

// Round 3
// 800.980 us; speedup vs baseline: 1.5471x; 1.5471x over previous
//
#include <hip/hip_runtime.h>

// RNN: h_{t+1} = tanh(W h_t + w_bias + V x_t + v_bias)
// x: [S,B,I] f32; W: [H,H]; V: [H,I]; out = h_seq [S,B,H] ++ h_final [B,H]
// S=2048 B=2048 I=16 H=64.
//
// Mapping: 1 wave per batch row; lane j owns hidden unit j.
// R3 change: amdgpu_waves_per_eu(1,2). R1/R2 showed VGPR_Count 64/60 — the
// scheduler targets the max achievable occupancy (8 waves/EU for a 64-thread,
// 4.6KB-LDS kernel) and spills the 80 weight floats to fit 64 VGPRs. The grid
// only provides 2 waves/EU (2048 waves / 1024 SIMDs), so cap the target at 2
// -> 256-VGPR budget -> W/V rows stay resident.

constexpr int S = 2048, B = 2048, I = 16, H = 64;
constexpr int CH = 64;  // timesteps of x staged per chunk

__global__ __launch_bounds__(64)
__attribute__((amdgpu_waves_per_eu(1, 2)))
void rnn_fused(const float* __restrict__ x,
               const float* __restrict__ Wm,
               const float* __restrict__ wb,
               const float* __restrict__ Vm,
               const float* __restrict__ vb,
               float* __restrict__ out)
{
    const int j = threadIdx.x;   // 0..63 = hidden unit
    const int b = blockIdx.x;    // batch row

    __shared__ __align__(16) float xs[CH][I];  // 4 KB, wave-private
    __shared__ __align__(16) float hs[H];      // 256 B, wave-private

    // ---- W row j: 16 named float4 (64 VGPRs), V row j: 4 named float4 ----
    const float4* wrow = (const float4*)(Wm + j * H);
    const float4 w0 = wrow[0],  w1 = wrow[1],  w2 = wrow[2],  w3 = wrow[3];
    const float4 w4 = wrow[4],  w5 = wrow[5],  w6 = wrow[6],  w7 = wrow[7];
    const float4 w8 = wrow[8],  w9 = wrow[9],  w10 = wrow[10], w11 = wrow[11];
    const float4 w12 = wrow[12], w13 = wrow[13], w14 = wrow[14], w15 = wrow[15];
    const float4* vrow = (const float4*)(Vm + j * I);
    const float4 v0 = vrow[0], v1 = vrow[1], v2 = vrow[2], v3 = vrow[3];
    const float bias = wb[j] + vb[j];

    hs[j] = 0.0f;        // h0 = 0
    float h = 0.0f;

    float* op = out + (size_t)b * H + j;   // h_seq[t][b][j], stride B*H per t
    const float* xb = x + (size_t)b * I;   // x[t][b][i], stride B*I per t

    for (int t0 = 0; t0 < S; t0 += CH) {
        // ---- stage x[t0 .. t0+CH) for this batch row (wave-private LDS) ----
#pragma unroll
        for (int m = 0; m < (CH * I) / (4 * 64); ++m) {  // 4 float4 per lane
            int q = j + 64 * m;          // float4 index in [0, 256)
            int tl = q >> 2, i4 = q & 3;
            float4 t4 = *(const float4*)(xb + (size_t)(t0 + tl) * (B * I) + i4 * 4);
            *(float4*)(&xs[tl][i4 * 4]) = t4;
        }
        // (no barrier: LDS tile is private to this wave)

        for (int tt = 0; tt < CH; ++tt) {
            const float4* h4 = (const float4*)hs;
            float a0 = bias, a1 = 0.f, a2 = 0.f, a3 = 0.f;
            float a4 = 0.f, a5 = 0.f, a6 = 0.f, a7 = 0.f;

            // W h: 16 broadcast ds_read_b128 + 64 FMAs, 8 independent chains
#define ACC_Q(q, A0, A1, A2, A3)                         \
            { float4 hq = h4[q];                         \
              A0 = fmaf(hq.x, w##q.x, A0);               \
              A1 = fmaf(hq.y, w##q.y, A1);               \
              A2 = fmaf(hq.z, w##q.z, A2);               \
              A3 = fmaf(hq.w, w##q.w, A3); }
            ACC_Q(0,  a0, a1, a2, a3)
            ACC_Q(1,  a4, a5, a6, a7)
            ACC_Q(2,  a0, a1, a2, a3)
            ACC_Q(3,  a4, a5, a6, a7)
            ACC_Q(4,  a0, a1, a2, a3)
            ACC_Q(5,  a4, a5, a6, a7)
            ACC_Q(6,  a0, a1, a2, a3)
            ACC_Q(7,  a4, a5, a6, a7)
            ACC_Q(8,  a0, a1, a2, a3)
            ACC_Q(9,  a4, a5, a6, a7)
            ACC_Q(10, a0, a1, a2, a3)
            ACC_Q(11, a4, a5, a6, a7)
            ACC_Q(12, a0, a1, a2, a3)
            ACC_Q(13, a4, a5, a6, a7)
            ACC_Q(14, a0, a1, a2, a3)
            ACC_Q(15, a4, a5, a6, a7)
#undef ACC_Q

            // V x_t: 4 broadcast ds_read_b128 + 16 FMAs
            const float4* x4 = (const float4*)xs[tt];
            {
                float4 xa = x4[0];
                a0 = fmaf(xa.x, v0.x, a0);  a1 = fmaf(xa.y, v0.y, a1);
                a2 = fmaf(xa.z, v0.z, a2);  a3 = fmaf(xa.w, v0.w, a3);
                float4 xbv = x4[1];
                a4 = fmaf(xbv.x, v1.x, a4); a5 = fmaf(xbv.y, v1.y, a5);
                a6 = fmaf(xbv.z, v1.z, a6); a7 = fmaf(xbv.w, v1.w, a7);
                float4 xc = x4[2];
                a0 = fmaf(xc.x, v2.x, a0);  a1 = fmaf(xc.y, v2.y, a1);
                a2 = fmaf(xc.z, v2.z, a2);  a3 = fmaf(xc.w, v2.w, a3);
                float4 xd = x4[3];
                a4 = fmaf(xd.x, v3.x, a4);  a5 = fmaf(xd.y, v3.y, a5);
                a6 = fmaf(xd.z, v3.z, a6);  a7 = fmaf(xd.w, v3.w, a7);
            }

            float pre = ((a0 + a1) + (a2 + a3)) + ((a4 + a5) + (a6 + a7));

            // tanh(pre) = 1 - 2/(exp(2*pre)+1); exp via v_exp_f32 (exp2)
            float e = __builtin_amdgcn_exp2f(pre * 2.8853900817779268f);
            float r = __builtin_amdgcn_rcpf(e + 1.0f);
            h = fmaf(-2.0f, r, 1.0f);

            hs[j] = h;                               // feed next step
            *op = h;                                 // h_seq store, coalesced
            op += B * H;
        }
    }
    // final h (second tuple element), after h_seq
    out[(size_t)S * B * H + (size_t)b * H + j] = h;
}

extern "C" void kernel_launch(void* const* d_in, const int* in_sizes, int n_in,
                              void* d_out, int out_size, void* d_ws, size_t ws_size,
                              hipStream_t stream) {
    const float* x  = (const float*)d_in[0];
    const float* Wm = (const float*)d_in[1];
    const float* wb = (const float*)d_in[2];
    const float* Vm = (const float*)d_in[3];
    const float* vb = (const float*)d_in[4];
    float* out = (float*)d_out;

    rnn_fused<<<B, 64, 0, stream>>>(x, Wm, wb, Vm, vb, out);
}

// Round 4
// 613.971 us; speedup vs baseline: 2.0183x; 1.3046x over previous
//
#include <hip/hip_runtime.h>

// RNN: h_{t+1} = tanh(W h_t + w_bias + V x_t + v_bias)
// x: [S,B,I] f32; W: [H,H]; V: [H,I]; out = h_seq [S,B,H] ++ h_final [B,H]
// S=2048 B=2048 I=16 H=64.
//
// Mapping: 1 wave per batch row; lane j owns hidden unit j.
// R4 change: packed fp16 v_dot2_f32_f16 (f32 accumulate) for both W·h and
// V·x. Halves MAC instructions (80->40), LDS reads (20->10), and weight
// VGPRs (80->40, killing the R1-R3 remat problem). fp32 formulation was
// issue-bound at ~2.3x the minimal instruction count with no path below
// ~330 us; fp16-dot floor is ~190 us issue + latency.

typedef _Float16 half2v __attribute__((ext_vector_type(2)));
typedef _Float16 half4v __attribute__((ext_vector_type(4)));
typedef _Float16 half8v __attribute__((ext_vector_type(8)));

constexpr int S = 2048, B = 2048, I = 16, H = 64;
constexpr int CH = 64;  // timesteps of x staged per chunk

#if defined(__has_builtin)
#if __has_builtin(__builtin_amdgcn_fdot2)
#define FDOT2(a, b, c) __builtin_amdgcn_fdot2((a), (b), (c), false)
#endif
#endif
#ifndef FDOT2
static __device__ __forceinline__ float fdot2_fb(half2v a, half2v b, float c) {
    return fmaf((float)a.x, (float)b.x, fmaf((float)a.y, (float)b.y, c));
}
#define FDOT2(a, b, c) fdot2_fb((a), (b), (c))
#endif

__global__ __launch_bounds__(64)
__attribute__((amdgpu_waves_per_eu(1, 2)))
void rnn_fused(const float* __restrict__ x,
               const float* __restrict__ Wm,
               const float* __restrict__ wb,
               const float* __restrict__ Vm,
               const float* __restrict__ vb,
               float* __restrict__ out)
{
    const int j = threadIdx.x;   // 0..63 = hidden unit
    const int b = blockIdx.x;    // batch row

    __shared__ __align__(16) _Float16 xsh[CH][I];  // 2 KB, wave-private
    __shared__ __align__(16) _Float16 hs[H];       // 128 B, wave-private

    // ---- W row j as 32 packed half2 (RNE converts), V row j as 8 ----
    const float4* wrow = (const float4*)(Wm + j * H);
    half2v W2[32];
#pragma unroll
    for (int c = 0; c < 16; ++c) {
        float4 t = wrow[c];
        half2v lo, hi;
        lo.x = (_Float16)t.x; lo.y = (_Float16)t.y;
        hi.x = (_Float16)t.z; hi.y = (_Float16)t.w;
        W2[2 * c] = lo; W2[2 * c + 1] = hi;
    }
    const float4* vrow = (const float4*)(Vm + j * I);
    half2v V2[8];
#pragma unroll
    for (int c = 0; c < 4; ++c) {
        float4 t = vrow[c];
        half2v lo, hi;
        lo.x = (_Float16)t.x; lo.y = (_Float16)t.y;
        hi.x = (_Float16)t.z; hi.y = (_Float16)t.w;
        V2[2 * c] = lo; V2[2 * c + 1] = hi;
    }
    const float bias = wb[j] + vb[j];

    hs[j] = (_Float16)0.0f;   // h0 = 0
    float h = 0.0f;

    const float* xb = x + (size_t)b * I;       // x[t][b][i]
    float* ob = out + (size_t)b * H + j;       // h_seq[t][b][j]

    for (int t0 = 0; t0 < S; t0 += CH) {
        // ---- stage x[t0..t0+CH) as fp16 (wave-private LDS, no barrier) ----
#pragma unroll
        for (int m = 0; m < (CH * I) / (4 * 64); ++m) {  // 4 float4 per lane
            int q = j + 64 * m;          // float4 index in [0, 256)
            int tl = q >> 2, i4 = q & 3;
            float4 t4 = *(const float4*)(xb + (size_t)(t0 + tl) * (B * I) + i4 * 4);
            half4v p;
            p.x = (_Float16)t4.x; p.y = (_Float16)t4.y;
            p.z = (_Float16)t4.z; p.w = (_Float16)t4.w;
            *(half4v*)(&xsh[tl][i4 * 4]) = p;   // ds_write_b64
        }

        for (int tt = 0; tt < CH; ++tt) {
            const half8v* hv = (const half8v*)hs;            // 8 x b128
            const half8v* xv = (const half8v*)(&xsh[tt][0]); // 2 x b128

            float a0 = bias, a1 = 0.f, a2 = 0.f, a3 = 0.f;
            float a4 = 0.f, a5 = 0.f, a6 = 0.f, a7 = 0.f;

            // W h: block c covers k=8c..8c+7 -> W2[4c..4c+3]; 8 chains
#define BLK(c, A0, A1, A2, A3)                                   \
            { half8v q = hv[c];                                  \
              half2v p0; p0.x = q[0]; p0.y = q[1];               \
              half2v p1; p1.x = q[2]; p1.y = q[3];               \
              half2v p2; p2.x = q[4]; p2.y = q[5];               \
              half2v p3; p3.x = q[6]; p3.y = q[7];               \
              A0 = FDOT2(p0, W2[4 * c + 0], A0);                 \
              A1 = FDOT2(p1, W2[4 * c + 1], A1);                 \
              A2 = FDOT2(p2, W2[4 * c + 2], A2);                 \
              A3 = FDOT2(p3, W2[4 * c + 3], A3); }
            BLK(0, a0, a1, a2, a3)
            BLK(1, a4, a5, a6, a7)
            BLK(2, a0, a1, a2, a3)
            BLK(3, a4, a5, a6, a7)
            BLK(4, a0, a1, a2, a3)
            BLK(5, a4, a5, a6, a7)
            BLK(6, a0, a1, a2, a3)
            BLK(7, a4, a5, a6, a7)
#undef BLK

            // V x_t: 2 b128 reads + 8 dots
            {
                half8v q = xv[0];
                half2v p0; p0.x = q[0]; p0.y = q[1];
                half2v p1; p1.x = q[2]; p1.y = q[3];
                half2v p2; p2.x = q[4]; p2.y = q[5];
                half2v p3; p3.x = q[6]; p3.y = q[7];
                a0 = FDOT2(p0, V2[0], a0);
                a1 = FDOT2(p1, V2[1], a1);
                a2 = FDOT2(p2, V2[2], a2);
                a3 = FDOT2(p3, V2[3], a3);
            }
            {
                half8v q = xv[1];
                half2v p0; p0.x = q[0]; p0.y = q[1];
                half2v p1; p1.x = q[2]; p1.y = q[3];
                half2v p2; p2.x = q[4]; p2.y = q[5];
                half2v p3; p3.x = q[6]; p3.y = q[7];
                a4 = FDOT2(p0, V2[4], a4);
                a5 = FDOT2(p1, V2[5], a5);
                a6 = FDOT2(p2, V2[6], a6);
                a7 = FDOT2(p3, V2[7], a7);
            }

            float pre = ((a0 + a1) + (a2 + a3)) + ((a4 + a5) + (a6 + a7));

            // tanh(pre) = 1 - 2/(exp2(pre*2*log2e)+1)
            float e = __builtin_amdgcn_exp2f(pre * 2.8853900817779268f);
            float r = __builtin_amdgcn_rcpf(e + 1.0f);
            h = fmaf(-2.0f, r, 1.0f);

            hs[j] = (_Float16)h;                          // feed next step
            ob[(size_t)(t0 + tt) * (B * H)] = h;          // coalesced store
        }
    }
    // final h (second tuple element), after h_seq
    out[(size_t)S * B * H + (size_t)b * H + j] = h;
}

extern "C" void kernel_launch(void* const* d_in, const int* in_sizes, int n_in,
                              void* d_out, int out_size, void* d_ws, size_t ws_size,
                              hipStream_t stream) {
    const float* x  = (const float*)d_in[0];
    const float* Wm = (const float*)d_in[1];
    const float* wb = (const float*)d_in[2];
    const float* Vm = (const float*)d_in[3];
    const float* vb = (const float*)d_in[4];
    float* out = (float*)d_out;

    rnn_fused<<<B, 64, 0, stream>>>(x, Wm, wb, Vm, vb, out);
}

// Round 5
// 606.896 us; speedup vs baseline: 2.0418x; 1.0117x over previous
//
#include <hip/hip_runtime.h>

// RNN: h_{t+1} = tanh(W h_t + w_bias + V x_t + v_bias)
// x: [S,B,I] f32; W: [H,H]; V: [H,I]; out = h_seq [S,B,H] ++ h_final [B,H]
// S=2048 B=2048 I=16 H=64.
//
// Mapping: 1 wave per batch row; lane j owns hidden unit j. fp16 packed
// v_dot2_f32_f16 for W·h and V·x (f32 accumulate).
// R5 change (codegen cleanup, no structure change): R4 showed 287 VALU
// cyc/wave-step vs ~110 hand-counted — suspected half8v elementwise unpack
// junk. Fix: read LDS as uint4 (ds_read_b128) and __builtin_bit_cast each
// dword to half2v (register alias, no shuffles). Also pointer-increment
// store addressing and #pragma unroll 4 on the step loop.

typedef _Float16 half2v __attribute__((ext_vector_type(2)));
typedef _Float16 half4v __attribute__((ext_vector_type(4)));

constexpr int S = 2048, B = 2048, I = 16, H = 64;
constexpr int CH = 64;  // timesteps of x staged per chunk

#if defined(__has_builtin)
#if __has_builtin(__builtin_amdgcn_fdot2)
#define FDOT2(a, b, c) __builtin_amdgcn_fdot2((a), (b), (c), false)
#endif
#endif
#ifndef FDOT2
static __device__ __forceinline__ float fdot2_fb(half2v a, half2v b, float c) {
    return fmaf((float)a.x, (float)b.x, fmaf((float)a.y, (float)b.y, c));
}
#define FDOT2(a, b, c) fdot2_fb((a), (b), (c))
#endif

__global__ __launch_bounds__(64)
__attribute__((amdgpu_waves_per_eu(1, 2)))
void rnn_fused(const float* __restrict__ x,
               const float* __restrict__ Wm,
               const float* __restrict__ wb,
               const float* __restrict__ Vm,
               const float* __restrict__ vb,
               float* __restrict__ out)
{
    const int j = threadIdx.x;   // 0..63 = hidden unit
    const int b = blockIdx.x;    // batch row

    __shared__ __align__(16) _Float16 xsh[CH][I];  // 2 KB, wave-private
    __shared__ __align__(16) _Float16 hs[H];       // 128 B, wave-private

    // ---- W row j as 32 packed half2 (40 VGPRs incl. V), RNE converts ----
    const float4* wrow = (const float4*)(Wm + j * H);
    half2v W2[32];
#pragma unroll
    for (int c = 0; c < 16; ++c) {
        float4 t = wrow[c];
        half2v lo, hi;
        lo.x = (_Float16)t.x; lo.y = (_Float16)t.y;
        hi.x = (_Float16)t.z; hi.y = (_Float16)t.w;
        W2[2 * c] = lo; W2[2 * c + 1] = hi;
    }
    const float4* vrow = (const float4*)(Vm + j * I);
    half2v V2[8];
#pragma unroll
    for (int c = 0; c < 4; ++c) {
        float4 t = vrow[c];
        half2v lo, hi;
        lo.x = (_Float16)t.x; lo.y = (_Float16)t.y;
        hi.x = (_Float16)t.z; hi.y = (_Float16)t.w;
        V2[2 * c] = lo; V2[2 * c + 1] = hi;
    }
    const float bias = wb[j] + vb[j];

    hs[j] = (_Float16)0.0f;   // h0 = 0
    float h = 0.0f;

    const float* xb = x + (size_t)b * I;       // x[t][b][i]
    float* op = out + (size_t)b * H + j;       // h_seq[t][b][j]

    const uint4* hv = (const uint4*)hs;        // 8 x ds_read_b128 (broadcast)

    for (int t0 = 0; t0 < S; t0 += CH) {
        // ---- stage x[t0..t0+CH) as fp16 (wave-private LDS, no barrier) ----
#pragma unroll
        for (int m = 0; m < (CH * I) / (4 * 64); ++m) {  // 4 float4 per lane
            int q = j + 64 * m;          // float4 index in [0, 256)
            int tl = q >> 2, i4 = q & 3;
            float4 t4 = *(const float4*)(xb + (size_t)(t0 + tl) * (B * I) + i4 * 4);
            half4v p;
            p.x = (_Float16)t4.x; p.y = (_Float16)t4.y;
            p.z = (_Float16)t4.z; p.w = (_Float16)t4.w;
            *(half4v*)(&xsh[tl][i4 * 4]) = p;   // ds_write_b64
        }

#pragma unroll 4
        for (int tt = 0; tt < CH; ++tt) {
            const uint4* xv = (const uint4*)(&xsh[tt][0]);  // 2 x b128

            float a0 = bias, a1 = 0.f, a2 = 0.f, a3 = 0.f;
            float a4 = 0.f, a5 = 0.f, a6 = 0.f, a7 = 0.f;

            // W h: block c covers k=8c..8c+7 -> W2[4c..4c+3]; 8 acc chains.
            // uint4 from ds_read_b128; each dword bit-cast to half2 (free).
#define BLK(c, A0, A1, A2, A3)                                       \
            { uint4 q = hv[c];                                       \
              A0 = FDOT2(__builtin_bit_cast(half2v, q.x),            \
                         W2[4 * c + 0], A0);                         \
              A1 = FDOT2(__builtin_bit_cast(half2v, q.y),            \
                         W2[4 * c + 1], A1);                         \
              A2 = FDOT2(__builtin_bit_cast(half2v, q.z),            \
                         W2[4 * c + 2], A2);                         \
              A3 = FDOT2(__builtin_bit_cast(half2v, q.w),            \
                         W2[4 * c + 3], A3); }
            BLK(0, a0, a1, a2, a3)
            BLK(1, a4, a5, a6, a7)
            BLK(2, a0, a1, a2, a3)
            BLK(3, a4, a5, a6, a7)
            BLK(4, a0, a1, a2, a3)
            BLK(5, a4, a5, a6, a7)
            BLK(6, a0, a1, a2, a3)
            BLK(7, a4, a5, a6, a7)
#undef BLK

            // V x_t: 2 b128 reads + 8 dots
            {
                uint4 q = xv[0];
                a0 = FDOT2(__builtin_bit_cast(half2v, q.x), V2[0], a0);
                a1 = FDOT2(__builtin_bit_cast(half2v, q.y), V2[1], a1);
                a2 = FDOT2(__builtin_bit_cast(half2v, q.z), V2[2], a2);
                a3 = FDOT2(__builtin_bit_cast(half2v, q.w), V2[3], a3);
            }
            {
                uint4 q = xv[1];
                a4 = FDOT2(__builtin_bit_cast(half2v, q.x), V2[4], a4);
                a5 = FDOT2(__builtin_bit_cast(half2v, q.y), V2[5], a5);
                a6 = FDOT2(__builtin_bit_cast(half2v, q.z), V2[6], a6);
                a7 = FDOT2(__builtin_bit_cast(half2v, q.w), V2[7], a7);
            }

            float pre = ((a0 + a1) + (a2 + a3)) + ((a4 + a5) + (a6 + a7));

            // tanh(pre) = 1 - 2/(exp2(pre*2*log2e)+1)
            float e = __builtin_amdgcn_exp2f(pre * 2.8853900817779268f);
            float r = __builtin_amdgcn_rcpf(e + 1.0f);
            h = fmaf(-2.0f, r, 1.0f);

            hs[j] = (_Float16)h;     // feed next step (wave-synchronous)
            *op = h;                 // coalesced 256B/wave store
            op += B * H;
        }
    }
    // final h (second tuple element), after h_seq
    out[(size_t)S * B * H + (size_t)b * H + j] = h;
}

extern "C" void kernel_launch(void* const* d_in, const int* in_sizes, int n_in,
                              void* d_out, int out_size, void* d_ws, size_t ws_size,
                              hipStream_t stream) {
    const float* x  = (const float*)d_in[0];
    const float* Wm = (const float*)d_in[1];
    const float* wb = (const float*)d_in[2];
    const float* Vm = (const float*)d_in[3];
    const float* vb = (const float*)d_in[4];
    float* out = (float*)d_out;

    rnn_fused<<<B, 64, 0, stream>>>(x, Wm, wb, Vm, vb, out);
}